// Round 5
// baseline (324.442 us; speedup 1.0000x reference)
//
#include <hip/hip_runtime.h>
#include <math.h>

#define BATCH   64
#define CH      256
#define RCH     64
#define HW      3136          // 56*56 floats per plane
#define HWF4    784           // f4 per plane (3136/4)
#define NBLK    256           // one block per CU (cooperative co-residency)
#define NTHR    1024          // 16 waves/block
#define PPB     64            // planes per block
#define PPW     4             // planes per wave
#define NREG    5             // f4 wave-strides held in registers per plane
#define LDSPL   63            // planes whose stride-5 is LDS-held

typedef float f4 __attribute__((ext_vector_type(4)));

// Monotonic grid-barrier counter. NEVER reset: each call's blocks compute
// their release target as the next multiple of NBLK above their own arrival
// ticket, so the counter just keeps climbing across graph replays (and the
// 0xAA ws-poison can't touch it — it's a device global, not in d_ws).
__device__ int g_ctr = 0;

// Single persistent cooperative kernel:
//  phase 1: stream x once; plane sums; strides 0..4 -> regs, stride 5 -> LDS.
//  inline atomic grid barrier (no function call => hold[] stays in VGPRs).
//  phase 2: per-block excite (redundant across the 4 blocks of a batch).
//  phase 3: scale; held 49% from regs/LDS, rest re-read; nt stores.
__global__ __launch_bounds__(NTHR)
void se_fused(const float* __restrict__ x,
              const float* __restrict__ w1,
              const float* __restrict__ b1,
              const float* __restrict__ w2,
              const float* __restrict__ b2,
              float* __restrict__ out,
              float* __restrict__ s_ws) {
    const int bid   = blockIdx.x;
    const int tid   = threadIdx.x;
    const int w     = tid >> 6;
    const int lane  = tid & 63;
    const int batch = bid >> 2;          // 4 blocks per batch
    const int cbase = (bid & 3) * PPB;   // channel base of this block

    __shared__ f4    lds4[LDSPL * 64];   // 64512 B
    __shared__ float h_lds[RCH];         // 256 B
    __shared__ float g_lds[PPB];         // 256 B   (total 65024 <= 64 KB)

    f4 hold[PPW][NREG];                  // 80 data VGPRs, static-indexed only
    float psum[PPW];

    const f4* __restrict__ xb = (const f4*)x + (size_t)(bid * PPB) * HWF4;

    // ---------------- phase 1: pool + on-chip cache ----------------
    #pragma unroll
    for (int q = 0; q < PPW; ++q) {
        const int pl = w * PPW + q;                    // plane_local 0..63
        const f4* __restrict__ xp = xb + (size_t)pl * HWF4;
        float acc = 0.0f;
        #pragma unroll
        for (int st = 0; st < NREG; ++st) {
            f4 v = xp[st * 64 + lane];
            hold[q][st] = v;
            acc += (v.x + v.y) + (v.z + v.w);
        }
        {
            f4 v = xp[NREG * 64 + lane];               // stride 5 -> LDS
            if (pl < LDSPL) lds4[pl * 64 + lane] = v;
            acc += (v.x + v.y) + (v.z + v.w);
        }
        #pragma unroll
        for (int st = NREG + 1; st < 12; ++st) {       // strides 6..11
            f4 v = xp[st * 64 + lane];
            acc += (v.x + v.y) + (v.z + v.w);
        }
        if (lane < 16) {                               // tail: 784 = 12*64+16
            f4 v = xp[768 + lane];
            acc += (v.x + v.y) + (v.z + v.w);
        }
        psum[q] = acc;
    }
    #pragma unroll
    for (int q = 0; q < PPW; ++q) {
        float a = psum[q];
        #pragma unroll
        for (int off = 32; off > 0; off >>= 1)
            a += __shfl_down(a, off, 64);
        if (lane == 0)
            s_ws[bid * PPB + w * PPW + q] = a * (1.0f / (float)HW);
    }

    // ---------------- inline grid barrier (no spill) ----------------
    __threadfence();                     // release: publish s_ws
    __syncthreads();                     // whole block has arrived
    if (tid == 0) {
        int ticket = __hip_atomic_fetch_add(&g_ctr, 1, __ATOMIC_ACQ_REL,
                                            __HIP_MEMORY_SCOPE_AGENT);
        const int target = ((ticket >> 8) + 1) << 8;   // next multiple of 256
        while (__hip_atomic_load(&g_ctr, __ATOMIC_ACQUIRE,
                                 __HIP_MEMORY_SCOPE_AGENT) < target)
            __builtin_amdgcn_s_sleep(2);
    }
    __syncthreads();
    __threadfence();                     // acquire: see other blocks' s_ws

    // ---------------- phase 2: excite (per block, redundant x4) ----------
    if (tid < RCH) {
        float acc = b1[tid];
        const float* __restrict__ wr = w1 + tid * CH;
        const float* __restrict__ sb = s_ws + batch * CH;
        #pragma unroll 8
        for (int c = 0; c < CH; ++c) acc = fmaf(wr[c], sb[c], acc);
        h_lds[tid] = fmaxf(acc, 0.0f);
    }
    __syncthreads();
    if (tid < PPB) {
        const int c = cbase + tid;
        float acc = b2[c];
        const float* __restrict__ wr = w2 + c * RCH;
        #pragma unroll 8
        for (int r = 0; r < RCH; ++r) acc = fmaf(wr[r], h_lds[r], acc);
        g_lds[tid] = 1.0f / (1.0f + expf(-acc));
    }
    __syncthreads();

    // ---------------- phase 3: scale + store ----------------
    f4* __restrict__ ob = (f4*)out + (size_t)(bid * PPB) * HWF4;
    #pragma unroll
    for (int q = 0; q < PPW; ++q) {
        const int pl = w * PPW + q;
        const f4* __restrict__ xp = xb + (size_t)pl * HWF4;
        f4* __restrict__ op = ob + (size_t)pl * HWF4;
        const float gg = g_lds[pl];

        #pragma unroll
        for (int st = 0; st < NREG; ++st) {
            f4 v = hold[q][st];
            v.x *= gg; v.y *= gg; v.z *= gg; v.w *= gg;
            __builtin_nontemporal_store(v, op + st * 64 + lane);
        }
        {
            f4 v = (pl < LDSPL) ? lds4[pl * 64 + lane]
                                : xp[NREG * 64 + lane];
            v.x *= gg; v.y *= gg; v.z *= gg; v.w *= gg;
            __builtin_nontemporal_store(v, op + NREG * 64 + lane);
        }
        #pragma unroll
        for (int st = NREG + 1; st < 12; ++st) {
            f4 v = xp[st * 64 + lane];
            v.x *= gg; v.y *= gg; v.z *= gg; v.w *= gg;
            __builtin_nontemporal_store(v, op + st * 64 + lane);
        }
        if (lane < 16) {
            f4 v = xp[768 + lane];
            v.x *= gg; v.y *= gg; v.z *= gg; v.w *= gg;
            __builtin_nontemporal_store(v, op + 768 + lane);
        }
    }
}

extern "C" void kernel_launch(void* const* d_in, const int* in_sizes, int n_in,
                              void* d_out, int out_size, void* d_ws, size_t ws_size,
                              hipStream_t stream) {
    const float* x  = (const float*)d_in[0];
    const float* w1 = (const float*)d_in[1];
    const float* b1 = (const float*)d_in[2];
    const float* w2 = (const float*)d_in[3];
    const float* b2 = (const float*)d_in[4];
    float* out  = (float*)d_out;
    float* s_ws = (float*)d_ws;          // 16384 floats = 64 KB

    void* args[] = { (void*)&x, (void*)&w1, (void*)&b1, (void*)&w2,
                     (void*)&b2, (void*)&out, (void*)&s_ws };
    hipLaunchCooperativeKernel((const void*)se_fused,
                               dim3(NBLK), dim3(NTHR),
                               args, 0, stream);
}

// Round 6
// 191.562 us; speedup vs baseline: 1.6937x; 1.6937x over previous
//
#include <hip/hip_runtime.h>
#include <math.h>

#define BATCH   64
#define CH      256
#define RCH     64
#define HW      3136          // 56*56 floats per plane
#define HWF4    784           // f4 per plane (3136/4)
#define NBLK    256           // one block per CU (cooperative co-residency)
#define NTHR    512           // 8 waves/block = 2 waves/SIMD at 1 block/CU
#define PPB     64            // planes per block
#define PPW     8             // planes per wave (64 planes / 8 waves)
#define NREG    5             // f4 wave-strides held in registers per plane
#define LDSPL   63            // planes whose stride-5 is LDS-held

typedef float f4 __attribute__((ext_vector_type(4)));

// Monotonic grid-barrier counter. NEVER reset: blocks compute their release
// target as the next multiple of NBLK above their own arrival ticket, so the
// counter climbs across graph replays (device global — ws poison can't hit it).
__device__ int g_ctr = 0;

// Single persistent cooperative kernel:
//  phase 1: stream x once; plane sums; strides 0..4 -> regs, stride 5 -> LDS.
//  inline atomic grid barrier (no function call => hold[] stays in VGPRs).
//  phase 2: per-block excite (redundant across the 4 blocks of a batch).
//  phase 3: scale; held ~49% from regs/LDS, rest re-read; nt stores.
//
// amdgpu_waves_per_eu(2,2): pin occupancy to 2 waves/SIMD (= exactly this
// one 8-wave block per CU) so the VGPR budget is 256/wave and the
// hold[8][5] f4 array (160 VGPRs) stays in registers. launch_bounds alone
// cannot do this — its 2nd arg is only a lower bound on waves/EU, and the
// default occupancy target (8/EU) capped us at 64 VGPRs => full spill (R4/R5).
__global__ __launch_bounds__(NTHR) __attribute__((amdgpu_waves_per_eu(2, 2)))
void se_fused(const float* __restrict__ x,
              const float* __restrict__ w1,
              const float* __restrict__ b1,
              const float* __restrict__ w2,
              const float* __restrict__ b2,
              float* __restrict__ out,
              float* __restrict__ s_ws) {
    const int bid   = blockIdx.x;
    const int tid   = threadIdx.x;
    const int w     = tid >> 6;
    const int lane  = tid & 63;
    const int batch = bid >> 2;          // 4 blocks per batch
    const int cbase = (bid & 3) * PPB;   // channel base of this block

    __shared__ f4    lds4[LDSPL * 64];   // 64512 B
    __shared__ float h_lds[RCH];         // 256 B
    __shared__ float g_lds[PPB];         // 256 B   (total 65024 <= 64 KB)

    f4 hold[PPW][NREG];                  // 160 data VGPRs, static-indexed only
    float psum[PPW];

    const f4* __restrict__ xb = (const f4*)x + (size_t)(bid * PPB) * HWF4;

    // ---------------- phase 1: pool + on-chip cache ----------------
    #pragma unroll
    for (int q = 0; q < PPW; ++q) {
        const int pl = w * PPW + q;                    // plane_local 0..63
        const f4* __restrict__ xp = xb + (size_t)pl * HWF4;
        float acc = 0.0f;
        #pragma unroll
        for (int st = 0; st < NREG; ++st) {
            f4 v = xp[st * 64 + lane];
            hold[q][st] = v;
            acc += (v.x + v.y) + (v.z + v.w);
        }
        {
            f4 v = xp[NREG * 64 + lane];               // stride 5 -> LDS
            if (pl < LDSPL) lds4[pl * 64 + lane] = v;
            acc += (v.x + v.y) + (v.z + v.w);
        }
        #pragma unroll
        for (int st = NREG + 1; st < 12; ++st) {       // strides 6..11
            f4 v = xp[st * 64 + lane];
            acc += (v.x + v.y) + (v.z + v.w);
        }
        if (lane < 16) {                               // tail: 784 = 12*64+16
            f4 v = xp[768 + lane];
            acc += (v.x + v.y) + (v.z + v.w);
        }
        psum[q] = acc;
    }
    #pragma unroll
    for (int q = 0; q < PPW; ++q) {
        float a = psum[q];
        #pragma unroll
        for (int off = 32; off > 0; off >>= 1)
            a += __shfl_down(a, off, 64);
        if (lane == 0)
            s_ws[bid * PPB + w * PPW + q] = a * (1.0f / (float)HW);
    }

    // ---------------- inline grid barrier (no spill) ----------------
    __threadfence();                     // release: publish s_ws
    __syncthreads();                     // whole block has arrived
    if (tid == 0) {
        int ticket = __hip_atomic_fetch_add(&g_ctr, 1, __ATOMIC_ACQ_REL,
                                            __HIP_MEMORY_SCOPE_AGENT);
        const int target = ((ticket >> 8) + 1) << 8;   // next multiple of 256
        while (__hip_atomic_load(&g_ctr, __ATOMIC_ACQUIRE,
                                 __HIP_MEMORY_SCOPE_AGENT) < target)
            __builtin_amdgcn_s_sleep(2);
    }
    __syncthreads();
    __threadfence();                     // acquire: see other blocks' s_ws

    // ---------------- phase 2: excite (per block, redundant x4) ----------
    if (tid < RCH) {
        float acc = b1[tid];
        const float* __restrict__ wr = w1 + tid * CH;
        const float* __restrict__ sb = s_ws + batch * CH;
        #pragma unroll 8
        for (int c = 0; c < CH; ++c) acc = fmaf(wr[c], sb[c], acc);
        h_lds[tid] = fmaxf(acc, 0.0f);
    }
    __syncthreads();
    if (tid < PPB) {
        const int c = cbase + tid;
        float acc = b2[c];
        const float* __restrict__ wr = w2 + c * RCH;
        #pragma unroll 8
        for (int r = 0; r < RCH; ++r) acc = fmaf(wr[r], h_lds[r], acc);
        g_lds[tid] = 1.0f / (1.0f + expf(-acc));
    }
    __syncthreads();

    // ---------------- phase 3: scale + store ----------------
    f4* __restrict__ ob = (f4*)out + (size_t)(bid * PPB) * HWF4;
    #pragma unroll
    for (int q = 0; q < PPW; ++q) {
        const int pl = w * PPW + q;
        const f4* __restrict__ xp = xb + (size_t)pl * HWF4;
        f4* __restrict__ op = ob + (size_t)pl * HWF4;
        const float gg = g_lds[pl];

        #pragma unroll
        for (int st = 0; st < NREG; ++st) {
            f4 v = hold[q][st];
            v.x *= gg; v.y *= gg; v.z *= gg; v.w *= gg;
            __builtin_nontemporal_store(v, op + st * 64 + lane);
        }
        {
            f4 v = (pl < LDSPL) ? lds4[pl * 64 + lane]
                                : xp[NREG * 64 + lane];
            v.x *= gg; v.y *= gg; v.z *= gg; v.w *= gg;
            __builtin_nontemporal_store(v, op + NREG * 64 + lane);
        }
        #pragma unroll
        for (int st = NREG + 1; st < 12; ++st) {
            f4 v = xp[st * 64 + lane];
            v.x *= gg; v.y *= gg; v.z *= gg; v.w *= gg;
            __builtin_nontemporal_store(v, op + st * 64 + lane);
        }
        if (lane < 16) {
            f4 v = xp[768 + lane];
            v.x *= gg; v.y *= gg; v.z *= gg; v.w *= gg;
            __builtin_nontemporal_store(v, op + 768 + lane);
        }
    }
}

extern "C" void kernel_launch(void* const* d_in, const int* in_sizes, int n_in,
                              void* d_out, int out_size, void* d_ws, size_t ws_size,
                              hipStream_t stream) {
    const float* x  = (const float*)d_in[0];
    const float* w1 = (const float*)d_in[1];
    const float* b1 = (const float*)d_in[2];
    const float* w2 = (const float*)d_in[3];
    const float* b2 = (const float*)d_in[4];
    float* out  = (float*)d_out;
    float* s_ws = (float*)d_ws;          // 16384 floats = 64 KB

    void* args[] = { (void*)&x, (void*)&w1, (void*)&b1, (void*)&w2,
                     (void*)&b2, (void*)&out, (void*)&s_ws };
    hipLaunchCooperativeKernel((const void*)se_fused,
                               dim3(NBLK), dim3(NTHR),
                               args, 0, stream);
}

// Round 8
// 177.686 us; speedup vs baseline: 1.8259x; 1.0781x over previous
//
#include <hip/hip_runtime.h>
#include <math.h>

#define BATCH   64
#define CH      256
#define RCH     64
#define HW      3136          // 56*56 floats per plane
#define HWF4    784           // f4 per plane (3136/4)
#define NBLK    256           // one block per CU (cooperative co-residency)
#define NTHR    512           // 8 waves/block = 2 waves/SIMD at 1 block/CU
#define PPB     64            // planes per block
#define PPW     8             // planes per wave

typedef float  f4  __attribute__((ext_vector_type(4)));
typedef __fp16 hf2 __attribute__((ext_vector_type(2)));   // cvt_pkrtz's type

union H4 { uint2 u; hf2 h[2]; };

// Monotonic grid-barrier counter. Never reset: blocks release at the next
// multiple of NBLK above their arrival ticket, so it climbs across replays.
__device__ int g_ctr = 0;

// Single cooperative kernel. Per-CU holding of x across the grid sync:
//   strides 0-1  -> f32 registers   (64 VGPR)
//   strides 2-5  -> fp16 registers  (64 VGPR, v_cvt_pkrtz packed)
//   strides 6-9  -> fp16 LDS        (128 KiB)
//   strides 10-12 -> re-read from HBM in phase 3 (37.7 MB total)
// LDS is deliberately >80 KiB: observed rule (R4/R6) is that the VGPR budget
// = 512 / (LDS-implied waves/EU); 129.5 KiB forces 1 block/CU = 2 waves/EU
// = 256-VGPR budget, which is what keeps the hold arrays out of scratch.
__global__ __launch_bounds__(NTHR, 2)
void se_fused(const float* __restrict__ x,
              const float* __restrict__ w1,
              const float* __restrict__ b1,
              const float* __restrict__ w2,
              const float* __restrict__ b2,
              float* __restrict__ out,
              float* __restrict__ s_ws) {
    const int bid   = blockIdx.x;
    const int tid   = threadIdx.x;
    const int w     = tid >> 6;
    const int lane  = tid & 63;
    const int batch = bid >> 2;          // 4 blocks per batch
    const int cbase = (bid & 3) * PPB;   // channel base of this block

    __shared__ uint2 lds16[PPB][4][64];  // 131072 B: strides 6..9 as fp16
    __shared__ float sv[CH];             // 1024 B
    __shared__ float h_lds[RCH];         // 256 B
    __shared__ float g_lds[PPB];         // 256 B   (total 132608 <= 160 KiB)

    f4    hold32[PPW][2];                // 64 VGPR, static-indexed
    uint2 hold16[PPW][4];                // 64 VGPR, static-indexed
    float psum[PPW];

    const f4* __restrict__ xb = (const f4*)x + (size_t)(bid * PPB) * HWF4;

    // ---------------- phase 1: pool + on-chip cache ----------------
    #pragma unroll
    for (int q = 0; q < PPW; ++q) {
        const int pl = w * PPW + q;                    // plane_local 0..63
        const f4* __restrict__ xp = xb + (size_t)pl * HWF4;
        float acc = 0.0f;
        #pragma unroll
        for (int st = 0; st < 2; ++st) {               // f32 regs
            f4 v = xp[st * 64 + lane];
            hold32[q][st] = v;
            acc += (v.x + v.y) + (v.z + v.w);
        }
        #pragma unroll
        for (int st = 2; st < 6; ++st) {               // fp16 regs
            f4 v = xp[st * 64 + lane];
            H4 p;
            p.h[0] = __builtin_amdgcn_cvt_pkrtz(v.x, v.y);
            p.h[1] = __builtin_amdgcn_cvt_pkrtz(v.z, v.w);
            hold16[q][st - 2] = p.u;
            acc += (v.x + v.y) + (v.z + v.w);
        }
        #pragma unroll
        for (int st = 6; st < 10; ++st) {              // fp16 LDS
            f4 v = xp[st * 64 + lane];
            H4 p;
            p.h[0] = __builtin_amdgcn_cvt_pkrtz(v.x, v.y);
            p.h[1] = __builtin_amdgcn_cvt_pkrtz(v.z, v.w);
            lds16[pl][st - 6][lane] = p.u;
            acc += (v.x + v.y) + (v.z + v.w);
        }
        #pragma unroll
        for (int st = 10; st < 12; ++st) {             // not held
            f4 v = xp[st * 64 + lane];
            acc += (v.x + v.y) + (v.z + v.w);
        }
        if (lane < 16) {                               // tail: 784 = 12*64+16
            f4 v = xp[768 + lane];
            acc += (v.x + v.y) + (v.z + v.w);
        }
        psum[q] = acc;
    }
    #pragma unroll
    for (int q = 0; q < PPW; ++q) {
        float a = psum[q];
        #pragma unroll
        for (int off = 32; off > 0; off >>= 1)
            a += __shfl_down(a, off, 64);
        if (lane == 0)
            s_ws[bid * PPB + w * PPW + q] = a * (1.0f / (float)HW);
    }

    // ---------------- inline grid barrier ----------------
    __threadfence();                     // release: publish s_ws
    __syncthreads();                     // whole block has arrived
    if (tid == 0) {
        int ticket = __hip_atomic_fetch_add(&g_ctr, 1, __ATOMIC_ACQ_REL,
                                            __HIP_MEMORY_SCOPE_AGENT);
        const int target = ((ticket >> 8) + 1) << 8;   // next multiple of 256
        while (__hip_atomic_load(&g_ctr, __ATOMIC_ACQUIRE,
                                 __HIP_MEMORY_SCOPE_AGENT) < target)
            __builtin_amdgcn_s_sleep(2);
    }
    __syncthreads();
    __threadfence();                     // acquire: see other blocks' s_ws

    // ---------------- phase 2: excite (per block, redundant x4) ----------
    if (tid < CH) sv[tid] = s_ws[batch * CH + tid];
    __syncthreads();
    if (tid < RCH) {
        float acc = b1[tid];
        const float* __restrict__ wr = w1 + tid * CH;
        #pragma unroll 8
        for (int c = 0; c < CH; ++c) acc = fmaf(wr[c], sv[c], acc);
        h_lds[tid] = fmaxf(acc, 0.0f);
    }
    __syncthreads();
    if (tid < PPB) {
        const int c = cbase + tid;
        float acc = b2[c];
        const float* __restrict__ wr = w2 + c * RCH;
        #pragma unroll 8
        for (int r = 0; r < RCH; ++r) acc = fmaf(wr[r], h_lds[r], acc);
        g_lds[tid] = 1.0f / (1.0f + expf(-acc));
    }
    __syncthreads();

    // ---------------- phase 3: scale + store ----------------
    f4* __restrict__ ob = (f4*)out + (size_t)(bid * PPB) * HWF4;
    #pragma unroll
    for (int q = 0; q < PPW; ++q) {
        const int pl = w * PPW + q;
        const f4* __restrict__ xp = xb + (size_t)pl * HWF4;
        f4* __restrict__ op = ob + (size_t)pl * HWF4;
        const float gg = g_lds[pl];

        #pragma unroll
        for (int st = 0; st < 2; ++st) {               // f32 regs
            f4 v = hold32[q][st];
            v.x *= gg; v.y *= gg; v.z *= gg; v.w *= gg;
            __builtin_nontemporal_store(v, op + st * 64 + lane);
        }
        #pragma unroll
        for (int st = 2; st < 6; ++st) {               // fp16 regs
            H4 p; p.u = hold16[q][st - 2];
            f4 v;
            v.x = (float)p.h[0][0]; v.y = (float)p.h[0][1];
            v.z = (float)p.h[1][0]; v.w = (float)p.h[1][1];
            v.x *= gg; v.y *= gg; v.z *= gg; v.w *= gg;
            __builtin_nontemporal_store(v, op + st * 64 + lane);
        }
        #pragma unroll
        for (int st = 6; st < 10; ++st) {              // fp16 LDS
            H4 p; p.u = lds16[pl][st - 6][lane];
            f4 v;
            v.x = (float)p.h[0][0]; v.y = (float)p.h[0][1];
            v.z = (float)p.h[1][0]; v.w = (float)p.h[1][1];
            v.x *= gg; v.y *= gg; v.z *= gg; v.w *= gg;
            __builtin_nontemporal_store(v, op + st * 64 + lane);
        }
        #pragma unroll
        for (int st = 10; st < 12; ++st) {             // re-read
            f4 v = xp[st * 64 + lane];
            v.x *= gg; v.y *= gg; v.z *= gg; v.w *= gg;
            __builtin_nontemporal_store(v, op + st * 64 + lane);
        }
        if (lane < 16) {                               // tail re-read
            f4 v = xp[768 + lane];
            v.x *= gg; v.y *= gg; v.z *= gg; v.w *= gg;
            __builtin_nontemporal_store(v, op + 768 + lane);
        }
    }
}

extern "C" void kernel_launch(void* const* d_in, const int* in_sizes, int n_in,
                              void* d_out, int out_size, void* d_ws, size_t ws_size,
                              hipStream_t stream) {
    const float* x  = (const float*)d_in[0];
    const float* w1 = (const float*)d_in[1];
    const float* b1 = (const float*)d_in[2];
    const float* w2 = (const float*)d_in[3];
    const float* b2 = (const float*)d_in[4];
    float* out  = (float*)d_out;
    float* s_ws = (float*)d_ws;          // 16384 floats = 64 KB

    void* args[] = { (void*)&x, (void*)&w1, (void*)&b1, (void*)&w2,
                     (void*)&b2, (void*)&out, (void*)&s_ws };
    hipLaunchCooperativeKernel((const void*)se_fused,
                               dim3(NBLK), dim3(NTHR),
                               args, 0, stream);
}